// Round 1
// baseline (395.119 us; speedup 1.0000x reference)
//
#include <hip/hip_runtime.h>
#include <hip/hip_bf16.h>

// RPN head: conv3x3(512->512)+ReLU, then 1x1 cls(18)+2-way softmax and 1x1 bbox(36).
// Strategy: bf16 MFMA implicit GEMM for the 3x3 conv (143 GFLOP), fused epilogues.

typedef __bf16 bf16_t;
typedef __attribute__((ext_vector_type(8))) __bf16 bf16x8;
typedef __attribute__((ext_vector_type(4))) float f32x4;

#define HW 3800
#define XP_IMG (52 * 78 * 512)

__device__ __forceinline__ void gload_lds16(const bf16_t* g, char* l) {
  __builtin_amdgcn_global_load_lds(
      (const __attribute__((address_space(1))) unsigned int*)g,
      (__attribute__((address_space(3))) unsigned int*)l, 16, 0, 0);
}

// base_feat [8][512][50][76] f32 -> Xp [8][52][78][512] bf16 (halo already zeroed)
__global__ __launch_bounds__(256) void pad_nhwc(const float* __restrict__ x,
                                                bf16_t* __restrict__ Xp) {
  int t = blockIdx.x * 256 + threadIdx.x;   // 8*50*64*76 = 1,945,600 threads
  int w = t % 76; int r = t / 76;
  int cc8 = r % 64; r /= 64;
  int h = r % 50; int b = r / 50;
  const float* src = x + (((size_t)(b * 512 + cc8 * 8)) * 50 + h) * 76 + w;
  bf16x8 v;
#pragma unroll
  for (int j = 0; j < 8; ++j) v[j] = (bf16_t)src[(size_t)j * 50 * 76];
  *(bf16x8*)(Xp + ((size_t)(b * 52 + h + 1) * 78 + (w + 1)) * 512 + cc8 * 8) = v;
}

// conv_w [512][512][3][3] f32 -> Wt [9][co][ci] bf16
__global__ __launch_bounds__(256) void wtrans(const float* __restrict__ cw,
                                              bf16_t* __restrict__ Wt) {
  int t = blockIdx.x * 256 + threadIdx.x;   // 9*512*64 = 294,912 threads
  int ci8 = t % 64; int r = t / 64; int co = r % 512; int s = r / 512;
  bf16x8 v;
#pragma unroll
  for (int j = 0; j < 8; ++j)
    v[j] = (bf16_t)cw[(size_t)(co * 512 + ci8 * 8 + j) * 9 + s];
  *(bf16x8*)(Wt + ((size_t)(s * 512 + co)) * 512 + ci8 * 8) = v;
}

// cls_w [18][512], bbox_w [36][512] f32 -> Wht [512][64] f32 (co-major, padded)
__global__ __launch_bounds__(256) void whtrans(const float* __restrict__ clsw,
                                               const float* __restrict__ boxw,
                                               float* __restrict__ Wht) {
  int t = blockIdx.x * 256 + threadIdx.x;   // 512*64 = 32768 threads
  int co = t % 64; int ci = t / 64;
  float v = 0.f;
  if (co < 18) v = clsw[co * 512 + ci];
  else if (co < 54) v = boxw[(co - 18) * 512 + ci];
  Wht[ci * 64 + co] = v;
}

// implicit-GEMM conv3x3: C[co][pos] over tiles 128x128, BK=64, 4 waves (2x2).
__global__ __launch_bounds__(256) void conv3x3(const bf16_t* __restrict__ Xp,
                                               const bf16_t* __restrict__ Wt,
                                               const float* __restrict__ convb,
                                               bf16_t* __restrict__ rc) {
  __shared__ __align__(16) char smem[32768];  // A(weights):[0,16K) B(X):[16K,32K)
  const int t = threadIdx.x;
  const int lane = t & 63;
  const int wv = t >> 6;
  const int bid = blockIdx.x;
  const int co_base = (bid & 3) * 128;
  const int sp_tile = (bid >> 2) % 30;
  const int b = bid / 120;
  const int m_base = sp_tile * 128;

  // staging precompute: chunk d = i*256+t; row r=d>>3, phys chunk p=d&7,
  // logical chunk c = p ^ (r&7)  (XOR swizzle, rule 21: inverse-swz SOURCE).
  int aSrc[4], hB[4], wB[4], cB[4];
#pragma unroll
  for (int i = 0; i < 4; ++i) {
    int d = i * 256 + t;
    int r = d >> 3, p = d & 7, c = p ^ (r & 7);
    aSrc[i] = (co_base + r) * 512 + c * 8;
    int m = m_base + r; if (m > HW - 1) m = HW - 1;   // clamp tail (masked at store)
    hB[i] = m / 76; wB[i] = m - (m / 76) * 76; cB[i] = c * 8;
  }
  const bf16_t* XpB = Xp + (size_t)b * XP_IMG;

  const int wm = wv >> 1, wn = wv & 1;
  const int lm = lane & 15, lg = lane >> 4, lx = lane & 7;
  int aRow[4], bRow[4];
#pragma unroll
  for (int f = 0; f < 4; ++f) {
    aRow[f] = (wm * 64 + f * 16 + lm) * 128;
    bRow[f] = 16384 + (wn * 64 + f * 16 + lm) * 128;
  }

  f32x4 acc[4][4];
#pragma unroll
  for (int i = 0; i < 4; ++i)
#pragma unroll
    for (int j = 0; j < 4; ++j) acc[i][j] = (f32x4){0.f, 0.f, 0.f, 0.f};

  for (int s = 0; s < 9; ++s) {
    const int kh = s / 3, kw = s - kh * 3;
    const bf16_t* WtS = Wt + (size_t)s * (512 * 512);
    int spOff[4];
#pragma unroll
    for (int i = 0; i < 4; ++i)
      spOff[i] = ((hB[i] + kh) * 78 + (wB[i] + kw)) * 512 + cB[i];

    for (int cb = 0; cb < 8; ++cb) {
      __syncthreads();
#pragma unroll
      for (int i = 0; i < 4; ++i) {
        int d = i * 256 + t;
        gload_lds16(WtS + aSrc[i] + cb * 64, &smem[d * 16]);
      }
#pragma unroll
      for (int i = 0; i < 4; ++i) {
        int d = i * 256 + t;
        gload_lds16(XpB + spOff[i] + cb * 64, &smem[16384 + d * 16]);
      }
      __syncthreads();
#pragma unroll
      for (int ks = 0; ks < 2; ++ks) {
        const int koff = ((ks * 4 + lg) ^ lx) << 4;  // swizzled ds_read (2-way, free)
        bf16x8 af[4], bfr[4];
#pragma unroll
        for (int f = 0; f < 4; ++f) af[f] = *(const bf16x8*)&smem[aRow[f] + koff];
#pragma unroll
        for (int f = 0; f < 4; ++f) bfr[f] = *(const bf16x8*)&smem[bRow[f] + koff];
#pragma unroll
        for (int fa = 0; fa < 4; ++fa)
#pragma unroll
          for (int fb = 0; fb < 4; ++fb)
            acc[fa][fb] = __builtin_amdgcn_mfma_f32_16x16x32_bf16(
                af[fa], bfr[fb], acc[fa][fb], 0, 0, 0);
      }
    }
  }

  // epilogue: bias + ReLU, store rc[b][co][m] bf16 (lane-group coalesced)
  const size_t rcB = (size_t)b * 512 * HW;
#pragma unroll
  for (int fa = 0; fa < 4; ++fa) {
#pragma unroll
    for (int r = 0; r < 4; ++r) {
      const int co = co_base + wm * 64 + fa * 16 + lg * 4 + r;
      const float bias = convb[co];
#pragma unroll
      for (int fb = 0; fb < 4; ++fb) {
        const int m = m_base + wn * 64 + fb * 16 + lm;
        if (m < HW) {
          float v = acc[fa][fb][r] + bias;
          rc[rcB + (size_t)co * HW + m] = (bf16_t)(v > 0.f ? v : 0.f);
        }
      }
    }
  }
}

// 1x1 heads + 2-way softmax: thread per position; weights via uniform s_loads.
__global__ __launch_bounds__(64) void heads(const bf16_t* __restrict__ rc,
                                            const float* __restrict__ Wht,
                                            const float* __restrict__ clsb,
                                            const float* __restrict__ boxb,
                                            float* __restrict__ out) {
  const int P = blockIdx.x * 64 + threadIdx.x;  // 475*64 = 30400 exactly
  const int b = P / HW;
  const int m = P - b * HW;
  const bf16_t* x = rc + (size_t)b * 512 * HW + m;
  float acc[54];
#pragma unroll
  for (int i = 0; i < 54; ++i) acc[i] = 0.f;
#pragma unroll 4
  for (int ci = 0; ci < 512; ++ci) {
    const float xv = (float)x[(size_t)ci * HW];
    const float* wr = Wht + ci * 64;   // wave-uniform -> scalar loads
#pragma unroll
    for (int co = 0; co < 54; ++co) acc[co] = fmaf(wr[co], xv, acc[co]);
  }
  float* clsOut = out;                           // [8][18][3800]
  float* boxOut = out + (size_t)8 * 18 * HW;     // [8][36][3800]
#pragma unroll
  for (int a = 0; a < 9; ++a) {
    float s0 = acc[a] + clsb[a];
    float s1 = acc[9 + a] + clsb[9 + a];
    float mx = fmaxf(s0, s1);
    float e0 = expf(s0 - mx), e1 = expf(s1 - mx);
    float inv = 1.0f / (e0 + e1);
    clsOut[((size_t)(b * 18 + a)) * HW + m] = e0 * inv;
    clsOut[((size_t)(b * 18 + 9 + a)) * HW + m] = e1 * inv;
  }
#pragma unroll
  for (int c = 0; c < 36; ++c)
    boxOut[((size_t)(b * 36 + c)) * HW + m] = acc[18 + c] + boxb[c];
}

extern "C" void kernel_launch(void* const* d_in, const int* in_sizes, int n_in,
                              void* d_out, int out_size, void* d_ws, size_t ws_size,
                              hipStream_t stream) {
  (void)in_sizes; (void)n_in; (void)out_size; (void)ws_size;
  const float* base_feat = (const float*)d_in[0];
  const float* conv_w = (const float*)d_in[4];
  const float* conv_b = (const float*)d_in[5];
  const float* cls_w  = (const float*)d_in[6];
  const float* cls_b  = (const float*)d_in[7];
  const float* bbox_w = (const float*)d_in[8];
  const float* bbox_b = (const float*)d_in[9];

  char* ws = (char*)d_ws;
  bf16_t* Xp  = (bf16_t*)(ws);                 // 8*52*78*512*2   = 33,226,752 B
  bf16_t* Wt  = (bf16_t*)(ws + 33226752);      // 9*512*512*2     =  4,718,592 B
  bf16_t* rc  = (bf16_t*)(ws + 37945344);      // 8*512*3800*2    = 31,129,600 B
  float*  Wht = (float*)(ws + 69074944);       // 512*64*4        =    131,072 B

  hipMemsetAsync(ws, 0, 33226752, stream);     // zero halo of Xp
  hipLaunchKernelGGL(pad_nhwc, dim3(7600), dim3(256), 0, stream, base_feat, Xp);
  hipLaunchKernelGGL(wtrans,   dim3(1152), dim3(256), 0, stream, conv_w, Wt);
  hipLaunchKernelGGL(whtrans,  dim3(128),  dim3(256), 0, stream, cls_w, bbox_w, Wht);
  hipLaunchKernelGGL(conv3x3,  dim3(960),  dim3(256), 0, stream, Xp, Wt, conv_b, rc);
  hipLaunchKernelGGL(heads,    dim3(475),  dim3(64),  0, stream, rc, Wht, cls_b, bbox_b,
                     (float*)d_out);
}

// Round 2
// 273.956 us; speedup vs baseline: 1.4423x; 1.4423x over previous
//
#include <hip/hip_runtime.h>
#include <hip/hip_bf16.h>

// RPN head: conv3x3(512->512)+ReLU, then 1x1 cls(18)+2-way softmax and 1x1 bbox(36).
// bf16 MFMA implicit GEMM for the 3x3 conv (143 GFLOP); heads as MFMA GEMM over
// NHWC rc; softmax pairing solved via A-row permutation (pair (a,a+9) -> rows 2a,2a+1).

typedef __bf16 bf16_t;
typedef __attribute__((ext_vector_type(8))) __bf16 bf16x8;
typedef __attribute__((ext_vector_type(4))) __bf16 bf16x4;
typedef __attribute__((ext_vector_type(4))) float f32x4;

#define HW 3800
#define NPOS (8 * HW)
#define XP_IMG (52 * 78 * 512)

__device__ __forceinline__ void gload_lds16(const bf16_t* g, char* l) {
  __builtin_amdgcn_global_load_lds(
      (const __attribute__((address_space(1))) unsigned int*)g,
      (__attribute__((address_space(3))) unsigned int*)l, 16, 0, 0);
}

// base_feat [8][512][50][76] f32 -> Xp [8][52][78][512] bf16, halo written as zeros
__global__ __launch_bounds__(256) void pad_nhwc(const float* __restrict__ x,
                                                bf16_t* __restrict__ Xp) {
  int t = blockIdx.x * 256 + threadIdx.x;   // 8*52*78*64 = 2,076,672 exact
  int cc8 = t & 63; int r = t >> 6;
  int w = r % 78; r /= 78;
  int h = r % 52; int b = r / 52;
  bf16x8 v;
  if (h >= 1 && h <= 50 && w >= 1 && w <= 76) {
    const float* src = x + (((size_t)(b * 512 + cc8 * 8)) * 50 + (h - 1)) * 76 + (w - 1);
#pragma unroll
    for (int j = 0; j < 8; ++j) v[j] = (bf16_t)src[(size_t)j * 50 * 76];
  } else {
#pragma unroll
    for (int j = 0; j < 8; ++j) v[j] = (bf16_t)0.f;
  }
  *(bf16x8*)(Xp + ((size_t)(b * 52 + h) * 78 + w) * 512 + cc8 * 8) = v;
}

// conv_w [512][512][3][3] f32 -> Wt [9][co][ci] bf16. Each thread owns one
// (co,ci): reads its contiguous 36B run; writes are wave-contiguous per s-plane.
__global__ __launch_bounds__(256) void wtrans(const float* __restrict__ cw,
                                              bf16_t* __restrict__ Wt) {
  int t = blockIdx.x * 256 + threadIdx.x;   // 512*512 = 262,144 exact
  int ci = t & 511; int co = t >> 9;
  const float* src = cw + ((size_t)co * 512 + ci) * 9;
#pragma unroll
  for (int s = 0; s < 9; ++s)
    Wt[((size_t)s * 512 + co) * 512 + ci] = (bf16_t)src[s];
}

// cls_w [18][512], bbox_w [36][512] f32 -> Whb [64][512] bf16, rows permuted:
// row 2a   = cls logit0 channel a, row 2a+1 = cls logit1 channel a (a<9)
// rows 18..53 = bbox channels, rows 54..63 = zero pad.
__global__ __launch_bounds__(256) void whb_build(const float* __restrict__ clsw,
                                                 const float* __restrict__ boxw,
                                                 bf16_t* __restrict__ Whb) {
  int t = blockIdx.x * 256 + threadIdx.x;   // 64*512 = 32768
  int ci = t & 511; int row = t >> 9;
  float v = 0.f;
  if (row < 18) {
    int a = row >> 1, logit = row & 1;
    v = clsw[(logit * 9 + a) * 512 + ci];
  } else if (row < 54) {
    v = boxw[(row - 18) * 512 + ci];
  }
  Whb[(size_t)row * 512 + ci] = (bf16_t)v;
}

// implicit-GEMM conv3x3: tiles 128co x 128pos, BK=64, 4 waves (2x2), XCD-swizzled.
__global__ __launch_bounds__(256) void conv3x3(const bf16_t* __restrict__ Xp,
                                               const bf16_t* __restrict__ Wt,
                                               const float* __restrict__ convb,
                                               bf16_t* __restrict__ rc2) {
  __shared__ __align__(16) char smem[32768];  // A(weights):[0,16K) B(X):[16K,32K)
  const int t = threadIdx.x;
  const int lane = t & 63;
  const int wv = t >> 6;
  // T1: bijective XCD swizzle, 960 % 8 == 0 -> each XCD gets one full image
  const int raw = blockIdx.x;
  const int wg = (raw & 7) * 120 + (raw >> 3);
  const int co_base = (wg & 3) * 128;
  const int sp_tile = (wg >> 2) % 30;
  const int b = wg / 120;
  const int m_base = sp_tile * 128;

  // staging: chunk d = i*256+t; row r=d>>3, phys chunk p=d&7, logical c = p^(r&7)
  int aSrc[4], hB[4], wB[4], cB[4];
#pragma unroll
  for (int i = 0; i < 4; ++i) {
    int d = i * 256 + t;
    int r = d >> 3, p = d & 7, c = p ^ (r & 7);
    aSrc[i] = (co_base + r) * 512 + c * 8;
    int m = m_base + r; if (m > HW - 1) m = HW - 1;   // clamp tail (masked at store)
    hB[i] = m / 76; wB[i] = m - (m / 76) * 76; cB[i] = c * 8;
  }
  const bf16_t* XpB = Xp + (size_t)b * XP_IMG;

  const int wm = wv >> 1, wn = wv & 1;
  const int lm = lane & 15, lg = lane >> 4, lx = lane & 7;
  int aRow[4], bRow[4];
#pragma unroll
  for (int f = 0; f < 4; ++f) {
    aRow[f] = (wm * 64 + f * 16 + lm) * 128;
    bRow[f] = 16384 + (wn * 64 + f * 16 + lm) * 128;
  }

  f32x4 acc[4][4];
#pragma unroll
  for (int i = 0; i < 4; ++i)
#pragma unroll
    for (int j = 0; j < 4; ++j) acc[i][j] = (f32x4){0.f, 0.f, 0.f, 0.f};

  for (int s = 0; s < 9; ++s) {
    const int kh = s / 3, kw = s - kh * 3;
    const bf16_t* WtS = Wt + (size_t)s * (512 * 512);
    int spOff[4];
#pragma unroll
    for (int i = 0; i < 4; ++i)
      spOff[i] = ((hB[i] + kh) * 78 + (wB[i] + kw)) * 512 + cB[i];

    for (int cb = 0; cb < 8; ++cb) {
      __syncthreads();
#pragma unroll
      for (int i = 0; i < 4; ++i) {
        int d = i * 256 + t;
        gload_lds16(WtS + aSrc[i] + cb * 64, &smem[d * 16]);
      }
#pragma unroll
      for (int i = 0; i < 4; ++i) {
        int d = i * 256 + t;
        gload_lds16(XpB + spOff[i] + cb * 64, &smem[16384 + d * 16]);
      }
      __syncthreads();
#pragma unroll
      for (int ks = 0; ks < 2; ++ks) {
        const int koff = ((ks * 4 + lg) ^ lx) << 4;  // swizzled ds_read (2-way, free)
        bf16x8 af[4], bfr[4];
#pragma unroll
        for (int f = 0; f < 4; ++f) af[f] = *(const bf16x8*)&smem[aRow[f] + koff];
#pragma unroll
        for (int f = 0; f < 4; ++f) bfr[f] = *(const bf16x8*)&smem[bRow[f] + koff];
#pragma unroll
        for (int fa = 0; fa < 4; ++fa)
#pragma unroll
          for (int fb = 0; fb < 4; ++fb)
            acc[fa][fb] = __builtin_amdgcn_mfma_f32_16x16x32_bf16(
                af[fa], bfr[fb], acc[fa][fb], 0, 0, 0);
      }
    }
  }

  // epilogue: bias + ReLU, store NHWC rc2[(b*HW+m)][co], 8B packed per (fa,fb)
#pragma unroll
  for (int fa = 0; fa < 4; ++fa) {
    const int co = co_base + wm * 64 + fa * 16 + lg * 4;
    float bias[4];
#pragma unroll
    for (int r = 0; r < 4; ++r) bias[r] = convb[co + r];
#pragma unroll
    for (int fb = 0; fb < 4; ++fb) {
      const int m = m_base + wn * 64 + fb * 16 + lm;
      if (m < HW) {
        bf16x4 v;
#pragma unroll
        for (int r = 0; r < 4; ++r) {
          float z = acc[fa][fb][r] + bias[r];
          v[r] = (bf16_t)(z > 0.f ? z : 0.f);
        }
        *(bf16x4*)(rc2 + ((size_t)b * HW + m) * 512 + co) = v;
      }
    }
  }
}

// heads: C[64co][128pos] = Whb[64][512] x rc2[pos][512], fused bias/softmax/store.
__global__ __launch_bounds__(256) void heads_mfma(const bf16_t* __restrict__ rc2,
                                                  const bf16_t* __restrict__ Whb,
                                                  const float* __restrict__ clsb,
                                                  const float* __restrict__ boxb,
                                                  float* __restrict__ out) {
  __shared__ __align__(16) char smem[24576];  // A:[0,8K) B:[8K,24K)
  const int t = threadIdx.x, lane = t & 63, wv = t >> 6;
  const int lm = lane & 15, lg = lane >> 4, lx = lane & 7;
  const int pos_base = blockIdx.x * 128;

  int aSrc[2], bSrc[4];
#pragma unroll
  for (int i = 0; i < 2; ++i) {
    int d = i * 256 + t;            // 0..511
    int r = d >> 3, p = d & 7, c = p ^ (r & 7);
    aSrc[i] = r * 512 + c * 8;
  }
#pragma unroll
  for (int i = 0; i < 4; ++i) {
    int d = i * 256 + t;            // 0..1023
    int r = d >> 3, p = d & 7, c = p ^ (r & 7);
    int pg = pos_base + r; if (pg > NPOS - 1) pg = NPOS - 1;  // tail clamp
    bSrc[i] = pg * 512 + c * 8;
  }

  f32x4 acc[4][2];
#pragma unroll
  for (int i = 0; i < 4; ++i)
#pragma unroll
    for (int j = 0; j < 2; ++j) acc[i][j] = (f32x4){0.f, 0.f, 0.f, 0.f};

  for (int cb = 0; cb < 8; ++cb) {
    __syncthreads();
#pragma unroll
    for (int i = 0; i < 2; ++i) {
      int d = i * 256 + t;
      gload_lds16(Whb + aSrc[i] + cb * 64, &smem[d * 16]);
    }
#pragma unroll
    for (int i = 0; i < 4; ++i) {
      int d = i * 256 + t;
      gload_lds16(rc2 + (size_t)bSrc[i] + cb * 64, &smem[8192 + d * 16]);
    }
    __syncthreads();
#pragma unroll
    for (int ks = 0; ks < 2; ++ks) {
      const int koff = ((ks * 4 + lg) ^ lx) << 4;
      bf16x8 af[4], bfr[2];
#pragma unroll
      for (int f = 0; f < 4; ++f)
        af[f] = *(const bf16x8*)&smem[(f * 16 + lm) * 128 + koff];
#pragma unroll
      for (int f = 0; f < 2; ++f)
        bfr[f] = *(const bf16x8*)&smem[8192 + (wv * 32 + f * 16 + lm) * 128 + koff];
#pragma unroll
      for (int fa = 0; fa < 4; ++fa)
#pragma unroll
        for (int fb = 0; fb < 2; ++fb)
          acc[fa][fb] = __builtin_amdgcn_mfma_f32_16x16x32_bf16(
              af[fa], bfr[fb], acc[fa][fb], 0, 0, 0);
    }
  }

  float* boxOut = out + (size_t)8 * 18 * HW;
#pragma unroll
  for (int fb = 0; fb < 2; ++fb) {
    const int pg = pos_base + wv * 32 + fb * 16 + lm;
    if (pg < NPOS) {
      const int b = pg / HW;
      const int m = pg - b * HW;
#pragma unroll
      for (int fa = 0; fa < 4; ++fa) {
        const int base = fa * 16 + lg * 4;
#pragma unroll
        for (int pr = 0; pr < 2; ++pr) {
          const int row0 = base + pr * 2;
          const float v0 = acc[fa][fb][pr * 2];
          const float v1 = acc[fa][fb][pr * 2 + 1];
          if (row0 < 18) {
            const int a = row0 >> 1;               // paired rows: (logit0, logit1)
            const float s0 = v0 + clsb[a];
            const float s1 = v1 + clsb[9 + a];
            const float mx = fmaxf(s0, s1);
            const float e0 = expf(s0 - mx), e1 = expf(s1 - mx);
            const float inv = 1.0f / (e0 + e1);
            out[((size_t)(b * 18 + a)) * HW + m] = e0 * inv;
            out[((size_t)(b * 18 + 9 + a)) * HW + m] = e1 * inv;
          } else if (row0 < 54) {
            const int c0 = row0 - 18;
            boxOut[((size_t)(b * 36 + c0)) * HW + m] = v0 + boxb[c0];
            boxOut[((size_t)(b * 36 + c0 + 1)) * HW + m] = v1 + boxb[c0 + 1];
          }
        }
      }
    }
  }
}

extern "C" void kernel_launch(void* const* d_in, const int* in_sizes, int n_in,
                              void* d_out, int out_size, void* d_ws, size_t ws_size,
                              hipStream_t stream) {
  (void)in_sizes; (void)n_in; (void)out_size; (void)ws_size;
  const float* base_feat = (const float*)d_in[0];
  const float* conv_w = (const float*)d_in[4];
  const float* conv_b = (const float*)d_in[5];
  const float* cls_w  = (const float*)d_in[6];
  const float* cls_b  = (const float*)d_in[7];
  const float* bbox_w = (const float*)d_in[8];
  const float* bbox_b = (const float*)d_in[9];

  char* ws = (char*)d_ws;
  bf16_t* Xp  = (bf16_t*)(ws);                 // 8*52*78*512*2   = 33,226,752 B
  bf16_t* Wt  = (bf16_t*)(ws + 33226752);      // 9*512*512*2     =  4,718,592 B
  bf16_t* rc2 = (bf16_t*)(ws + 37945344);      // 30400*512*2     = 31,129,600 B (NHWC)
  bf16_t* Whb = (bf16_t*)(ws + 69074944);      // 64*512*2        =     65,536 B

  hipLaunchKernelGGL(pad_nhwc,   dim3(8112), dim3(256), 0, stream, base_feat, Xp);
  hipLaunchKernelGGL(wtrans,     dim3(1024), dim3(256), 0, stream, conv_w, Wt);
  hipLaunchKernelGGL(whb_build,  dim3(128),  dim3(256), 0, stream, cls_w, bbox_w, Whb);
  hipLaunchKernelGGL(conv3x3,    dim3(960),  dim3(256), 0, stream, Xp, Wt, conv_b, rc2);
  hipLaunchKernelGGL(heads_mfma, dim3(238),  dim3(256), 0, stream, rc2, Whb, cls_b, bbox_b,
                     (float*)d_out);
}

// Round 3
// 198.445 us; speedup vs baseline: 1.9911x; 1.3805x over previous
//
#include <hip/hip_runtime.h>
#include <hip/hip_bf16.h>

// RPN head: conv3x3(512->512)+ReLU, then 1x1 cls(18)+2-way softmax and 1x1 bbox(36).
// bf16 MFMA implicit GEMM for the 3x3 conv (143 GFLOP); heads as MFMA GEMM over
// NHWC rc; softmax pairing solved via A-row permutation (pair (a,a+9) -> rows 2a,2a+1).

typedef __bf16 bf16_t;
typedef __attribute__((ext_vector_type(8))) __bf16 bf16x8;
typedef __attribute__((ext_vector_type(4))) __bf16 bf16x4;
typedef __attribute__((ext_vector_type(4))) float f32x4;

#define HW 3800
#define NPOS (8 * HW)
#define XP_IMG (52 * 78 * 512)

__device__ __forceinline__ void gload_lds16(const bf16_t* g, char* l) {
  __builtin_amdgcn_global_load_lds(
      (const __attribute__((address_space(1))) unsigned int*)g,
      (__attribute__((address_space(3))) unsigned int*)l, 16, 0, 0);
}

// base_feat [8][512][50][76] f32 -> Xp [8][52][78][512] bf16.
// Blocks 0..1599: (b, h, 128c chunk) LDS-transpose, coalesced reads AND writes.
// Blocks 1600..1615: zero the halo (h=0,51; w=0,77).
__global__ __launch_bounds__(256) void pad_nhwc(const float* __restrict__ x,
                                                bf16_t* __restrict__ Xp) {
  const int t = threadIdx.x;
  const int blk = blockIdx.x;
  if (blk < 1600) {
    __shared__ __align__(16) bf16_t tile[76][136];  // [w][c], 272B rows (16B-aligned)
    const int cb = blk & 3;
    int r = blk >> 2;
    const int h = r % 50, b = r / 50;
    // phase 1: 128c x 19(w4) float4 reads, coalesced along w; 2B scatter into LDS
#pragma unroll
    for (int it = 0; it < 10; ++it) {
      int idx = it * 256 + t;
      if (idx < 2432) {
        int c = idx / 19, w4 = idx - c * 19;
        const float4 v = *(const float4*)(x +
            (((size_t)(b * 512 + cb * 128 + c)) * 50 + h) * 76 + w4 * 4);
        tile[w4 * 4 + 0][c] = (bf16_t)v.x;
        tile[w4 * 4 + 1][c] = (bf16_t)v.y;
        tile[w4 * 4 + 2][c] = (bf16_t)v.z;
        tile[w4 * 4 + 3][c] = (bf16_t)v.w;
      }
    }
    __syncthreads();
    // phase 2: 76w x 16(c8) ds_read_b128 + coalesced 16B global writes
#pragma unroll
    for (int it = 0; it < 5; ++it) {
      int idx = it * 256 + t;
      if (idx < 1216) {
        int w = idx >> 4, c8 = idx & 15;
        bf16x8 v = *(const bf16x8*)&tile[w][c8 * 8];
        *(bf16x8*)(Xp + ((size_t)(b * 52 + h + 1) * 78 + (w + 1)) * 512 +
                   cb * 128 + c8 * 8) = v;
      }
    }
  } else {
    const int blk2 = blk - 1600;            // 16 halo blocks
    const int b = blk2 >> 1, half = blk2 & 1;
    bf16x8 z;
#pragma unroll
    for (int j = 0; j < 8; ++j) z[j] = (bf16_t)0.f;
#pragma unroll
    for (int it = 0; it < 32; ++it) {
      int idx = it * 256 + t;               // 128 pos-half x 64 c8
      int q = half * 128 + (idx >> 6);      // halo position 0..255
      int c8 = idx & 63;
      int h, w;
      if (q < 78)       { h = 0;           w = q; }
      else if (q < 156) { h = 51;          w = q - 78; }
      else if (q < 206) { h = q - 156 + 1; w = 0; }
      else              { h = q - 206 + 1; w = 77; }
      *(bf16x8*)(Xp + ((size_t)(b * 52 + h) * 78 + w) * 512 + c8 * 8) = z;
    }
  }
}

// conv_w [512][512][3][3] f32 -> Wt [9][co][ci] bf16. One block per co:
// coalesced 4608-f32 read into LDS, then 9 coalesced 1KB bf16 row writes.
__global__ __launch_bounds__(256) void wtrans(const float* __restrict__ cw,
                                              bf16_t* __restrict__ Wt) {
  __shared__ bf16_t lw[4608];
  const int t = threadIdx.x;
  const int co = blockIdx.x;
  const float* src = cw + (size_t)co * 4608;
#pragma unroll
  for (int it = 0; it < 18; ++it) {
    int idx = it * 256 + t;
    lw[idx] = (bf16_t)src[idx];
  }
  __syncthreads();
#pragma unroll
  for (int s = 0; s < 9; ++s) {
    int ci = t * 2;
    bf16_t v0 = lw[ci * 9 + s], v1 = lw[(ci + 1) * 9 + s];
    bf16_t* dst = Wt + ((size_t)s * 512 + co) * 512 + ci;
    dst[0] = v0; dst[1] = v1;
  }
}

// cls_w [18][512], bbox_w [36][512] f32 -> Whb [64][512] bf16, rows permuted:
// row 2a = cls logit0 ch a, row 2a+1 = cls logit1 ch a (a<9); 18..53 bbox; pad 0.
__global__ __launch_bounds__(256) void whb_build(const float* __restrict__ clsw,
                                                 const float* __restrict__ boxw,
                                                 bf16_t* __restrict__ Whb) {
  int t = blockIdx.x * 256 + threadIdx.x;   // 64*512 = 32768
  int ci = t & 511; int row = t >> 9;
  float v = 0.f;
  if (row < 18) {
    int a = row >> 1, logit = row & 1;
    v = clsw[(logit * 9 + a) * 512 + ci];
  } else if (row < 54) {
    v = boxw[(row - 18) * 512 + ci];
  }
  Whb[(size_t)row * 512 + ci] = (bf16_t)v;
}

// implicit-GEMM conv3x3: tiles 128co x 128pos, BK=64, 4 waves (2x2), XCD-swizzled.
__global__ __launch_bounds__(256) void conv3x3(const bf16_t* __restrict__ Xp,
                                               const bf16_t* __restrict__ Wt,
                                               const float* __restrict__ convb,
                                               bf16_t* __restrict__ rc2) {
  __shared__ __align__(16) char smem[32768];  // A(weights):[0,16K) B(X):[16K,32K)
  const int t = threadIdx.x;
  const int lane = t & 63;
  const int wv = t >> 6;
  // T1: bijective XCD swizzle, 960 % 8 == 0 -> each XCD gets one full image
  const int raw = blockIdx.x;
  const int wg = (raw & 7) * 120 + (raw >> 3);
  const int co_base = (wg & 3) * 128;
  const int sp_tile = (wg >> 2) % 30;
  const int b = wg / 120;
  const int m_base = sp_tile * 128;

  // staging: chunk d = i*256+t; row r=d>>3, phys chunk p=d&7, logical c = p^(r&7)
  int aSrc[4], hB[4], wB[4], cB[4];
#pragma unroll
  for (int i = 0; i < 4; ++i) {
    int d = i * 256 + t;
    int r = d >> 3, p = d & 7, c = p ^ (r & 7);
    aSrc[i] = (co_base + r) * 512 + c * 8;
    int m = m_base + r; if (m > HW - 1) m = HW - 1;   // clamp tail (masked at store)
    hB[i] = m / 76; wB[i] = m - (m / 76) * 76; cB[i] = c * 8;
  }
  const bf16_t* XpB = Xp + (size_t)b * XP_IMG;

  const int wm = wv >> 1, wn = wv & 1;
  const int lm = lane & 15, lg = lane >> 4, lx = lane & 7;
  int aRow[4], bRow[4];
#pragma unroll
  for (int f = 0; f < 4; ++f) {
    aRow[f] = (wm * 64 + f * 16 + lm) * 128;
    bRow[f] = 16384 + (wn * 64 + f * 16 + lm) * 128;
  }

  f32x4 acc[4][4];
#pragma unroll
  for (int i = 0; i < 4; ++i)
#pragma unroll
    for (int j = 0; j < 4; ++j) acc[i][j] = (f32x4){0.f, 0.f, 0.f, 0.f};

  for (int s = 0; s < 9; ++s) {
    const int kh = s / 3, kw = s - kh * 3;
    const bf16_t* WtS = Wt + (size_t)s * (512 * 512);
    int spOff[4];
#pragma unroll
    for (int i = 0; i < 4; ++i)
      spOff[i] = ((hB[i] + kh) * 78 + (wB[i] + kw)) * 512 + cB[i];

    for (int cb = 0; cb < 8; ++cb) {
      __syncthreads();
#pragma unroll
      for (int i = 0; i < 4; ++i) {
        int d = i * 256 + t;
        gload_lds16(WtS + aSrc[i] + cb * 64, &smem[d * 16]);
      }
#pragma unroll
      for (int i = 0; i < 4; ++i) {
        int d = i * 256 + t;
        gload_lds16(XpB + spOff[i] + cb * 64, &smem[16384 + d * 16]);
      }
      __syncthreads();
#pragma unroll
      for (int ks = 0; ks < 2; ++ks) {
        const int koff = ((ks * 4 + lg) ^ lx) << 4;  // swizzled ds_read (2-way, free)
        bf16x8 af[4], bfr[4];
#pragma unroll
        for (int f = 0; f < 4; ++f) af[f] = *(const bf16x8*)&smem[aRow[f] + koff];
#pragma unroll
        for (int f = 0; f < 4; ++f) bfr[f] = *(const bf16x8*)&smem[bRow[f] + koff];
#pragma unroll
        for (int fa = 0; fa < 4; ++fa)
#pragma unroll
          for (int fb = 0; fb < 4; ++fb)
            acc[fa][fb] = __builtin_amdgcn_mfma_f32_16x16x32_bf16(
                af[fa], bfr[fb], acc[fa][fb], 0, 0, 0);
      }
    }
  }

  // epilogue: bias + ReLU, store NHWC rc2[(b*HW+m)][co], 8B packed per (fa,fb)
#pragma unroll
  for (int fa = 0; fa < 4; ++fa) {
    const int co = co_base + wm * 64 + fa * 16 + lg * 4;
    float bias[4];
#pragma unroll
    for (int r = 0; r < 4; ++r) bias[r] = convb[co + r];
#pragma unroll
    for (int fb = 0; fb < 4; ++fb) {
      const int m = m_base + wn * 64 + fb * 16 + lm;
      if (m < HW) {
        bf16x4 v;
#pragma unroll
        for (int r = 0; r < 4; ++r) {
          float z = acc[fa][fb][r] + bias[r];
          v[r] = (bf16_t)(z > 0.f ? z : 0.f);
        }
        *(bf16x4*)(rc2 + ((size_t)b * HW + m) * 512 + co) = v;
      }
    }
  }
}

// heads: C[64co][128pos] = Whb[64][512] x rc2[pos][512], fused bias/softmax/store.
__global__ __launch_bounds__(256) void heads_mfma(const bf16_t* __restrict__ rc2,
                                                  const bf16_t* __restrict__ Whb,
                                                  const float* __restrict__ clsb,
                                                  const float* __restrict__ boxb,
                                                  float* __restrict__ out) {
  __shared__ __align__(16) char smem[24576];  // A:[0,8K) B:[8K,24K)
  const int t = threadIdx.x, lane = t & 63, wv = t >> 6;
  const int lm = lane & 15, lg = lane >> 4, lx = lane & 7;
  const int pos_base = blockIdx.x * 128;

  int aSrc[2], bSrc[4];
#pragma unroll
  for (int i = 0; i < 2; ++i) {
    int d = i * 256 + t;            // 0..511
    int r = d >> 3, p = d & 7, c = p ^ (r & 7);
    aSrc[i] = r * 512 + c * 8;
  }
#pragma unroll
  for (int i = 0; i < 4; ++i) {
    int d = i * 256 + t;            // 0..1023
    int r = d >> 3, p = d & 7, c = p ^ (r & 7);
    int pg = pos_base + r; if (pg > NPOS - 1) pg = NPOS - 1;  // tail clamp
    bSrc[i] = pg * 512 + c * 8;
  }

  f32x4 acc[4][2];
#pragma unroll
  for (int i = 0; i < 4; ++i)
#pragma unroll
    for (int j = 0; j < 2; ++j) acc[i][j] = (f32x4){0.f, 0.f, 0.f, 0.f};

  for (int cb = 0; cb < 8; ++cb) {
    __syncthreads();
#pragma unroll
    for (int i = 0; i < 2; ++i) {
      int d = i * 256 + t;
      gload_lds16(Whb + aSrc[i] + cb * 64, &smem[d * 16]);
    }
#pragma unroll
    for (int i = 0; i < 4; ++i) {
      int d = i * 256 + t;
      gload_lds16(rc2 + (size_t)bSrc[i] + cb * 64, &smem[8192 + d * 16]);
    }
    __syncthreads();
#pragma unroll
    for (int ks = 0; ks < 2; ++ks) {
      const int koff = ((ks * 4 + lg) ^ lx) << 4;
      bf16x8 af[4], bfr[2];
#pragma unroll
      for (int f = 0; f < 4; ++f)
        af[f] = *(const bf16x8*)&smem[(f * 16 + lm) * 128 + koff];
#pragma unroll
      for (int f = 0; f < 2; ++f)
        bfr[f] = *(const bf16x8*)&smem[8192 + (wv * 32 + f * 16 + lm) * 128 + koff];
#pragma unroll
      for (int fa = 0; fa < 4; ++fa)
#pragma unroll
        for (int fb = 0; fb < 2; ++fb)
          acc[fa][fb] = __builtin_amdgcn_mfma_f32_16x16x32_bf16(
              af[fa], bfr[fb], acc[fa][fb], 0, 0, 0);
    }
  }

  float* boxOut = out + (size_t)8 * 18 * HW;
#pragma unroll
  for (int fb = 0; fb < 2; ++fb) {
    const int pg = pos_base + wv * 32 + fb * 16 + lm;
    if (pg < NPOS) {
      const int b = pg / HW;
      const int m = pg - b * HW;
#pragma unroll
      for (int fa = 0; fa < 4; ++fa) {
        const int base = fa * 16 + lg * 4;
#pragma unroll
        for (int pr = 0; pr < 2; ++pr) {
          const int row0 = base + pr * 2;
          const float v0 = acc[fa][fb][pr * 2];
          const float v1 = acc[fa][fb][pr * 2 + 1];
          if (row0 < 18) {
            const int a = row0 >> 1;               // paired rows: (logit0, logit1)
            const float s0 = v0 + clsb[a];
            const float s1 = v1 + clsb[9 + a];
            const float mx = fmaxf(s0, s1);
            const float e0 = expf(s0 - mx), e1 = expf(s1 - mx);
            const float inv = 1.0f / (e0 + e1);
            out[((size_t)(b * 18 + a)) * HW + m] = e0 * inv;
            out[((size_t)(b * 18 + 9 + a)) * HW + m] = e1 * inv;
          } else if (row0 < 54) {
            const int c0 = row0 - 18;
            boxOut[((size_t)(b * 36 + c0)) * HW + m] = v0 + boxb[c0];
            boxOut[((size_t)(b * 36 + c0 + 1)) * HW + m] = v1 + boxb[c0 + 1];
          }
        }
      }
    }
  }
}

extern "C" void kernel_launch(void* const* d_in, const int* in_sizes, int n_in,
                              void* d_out, int out_size, void* d_ws, size_t ws_size,
                              hipStream_t stream) {
  (void)in_sizes; (void)n_in; (void)out_size; (void)ws_size;
  const float* base_feat = (const float*)d_in[0];
  const float* conv_w = (const float*)d_in[4];
  const float* conv_b = (const float*)d_in[5];
  const float* cls_w  = (const float*)d_in[6];
  const float* cls_b  = (const float*)d_in[7];
  const float* bbox_w = (const float*)d_in[8];
  const float* bbox_b = (const float*)d_in[9];

  char* ws = (char*)d_ws;
  bf16_t* Xp  = (bf16_t*)(ws);                 // 8*52*78*512*2   = 33,226,752 B
  bf16_t* Wt  = (bf16_t*)(ws + 33226752);      // 9*512*512*2     =  4,718,592 B
  bf16_t* rc2 = (bf16_t*)(ws + 37945344);      // 30400*512*2     = 31,129,600 B (NHWC)
  bf16_t* Whb = (bf16_t*)(ws + 69074944);      // 64*512*2        =     65,536 B

  hipLaunchKernelGGL(pad_nhwc,   dim3(1616), dim3(256), 0, stream, base_feat, Xp);
  hipLaunchKernelGGL(wtrans,     dim3(512),  dim3(256), 0, stream, conv_w, Wt);
  hipLaunchKernelGGL(whb_build,  dim3(128),  dim3(256), 0, stream, cls_w, bbox_w, Whb);
  hipLaunchKernelGGL(conv3x3,    dim3(960),  dim3(256), 0, stream, Xp, Wt, conv_b, rc2);
  hipLaunchKernelGGL(heads_mfma, dim3(238),  dim3(256), 0, stream, rc2, Whb, cls_b, bbox_b,
                     (float*)d_out);
}

// Round 4
// 162.149 us; speedup vs baseline: 2.4368x; 1.2238x over previous
//
#include <hip/hip_runtime.h>
#include <hip/hip_bf16.h>

// RPN head: conv3x3(512->512)+ReLU, then 1x1 cls(18)+2-way softmax and 1x1 bbox(36).
// conv = bf16 MFMA implicit GEMM, 256x256 tile, 8 waves, double-buffered LDS,
// 4-phase deep pipeline (issue-early stage / boundary-only vmcnt, setprio on MFMA).

typedef __bf16 bf16_t;
typedef __attribute__((ext_vector_type(8))) __bf16 bf16x8;
typedef __attribute__((ext_vector_type(4))) __bf16 bf16x4;
typedef __attribute__((ext_vector_type(4))) float f32x4;

#define HW 3800
#define NPOS (8 * HW)
#define XP_IMG (52 * 78 * 512)

__device__ __forceinline__ void gload_lds16(const bf16_t* g, char* l) {
  __builtin_amdgcn_global_load_lds(
      (const __attribute__((address_space(1))) unsigned int*)g,
      (__attribute__((address_space(3))) unsigned int*)l, 16, 0, 0);
}

// base_feat [8][512][50][76] f32 -> Xp [8][52][78][512] bf16.
__global__ __launch_bounds__(256) void pad_nhwc(const float* __restrict__ x,
                                                bf16_t* __restrict__ Xp) {
  const int t = threadIdx.x;
  const int blk = blockIdx.x;
  if (blk < 1600) {
    __shared__ __align__(16) bf16_t tile[76][136];  // [w][c], 272B rows
    const int cb = blk & 3;
    int r = blk >> 2;
    const int h = r % 50, b = r / 50;
#pragma unroll
    for (int it = 0; it < 10; ++it) {
      int idx = it * 256 + t;
      if (idx < 2432) {
        int c = idx / 19, w4 = idx - c * 19;
        const float4 v = *(const float4*)(x +
            (((size_t)(b * 512 + cb * 128 + c)) * 50 + h) * 76 + w4 * 4);
        tile[w4 * 4 + 0][c] = (bf16_t)v.x;
        tile[w4 * 4 + 1][c] = (bf16_t)v.y;
        tile[w4 * 4 + 2][c] = (bf16_t)v.z;
        tile[w4 * 4 + 3][c] = (bf16_t)v.w;
      }
    }
    __syncthreads();
#pragma unroll
    for (int it = 0; it < 5; ++it) {
      int idx = it * 256 + t;
      if (idx < 1216) {
        int w = idx >> 4, c8 = idx & 15;
        bf16x8 v = *(const bf16x8*)&tile[w][c8 * 8];
        *(bf16x8*)(Xp + ((size_t)(b * 52 + h + 1) * 78 + (w + 1)) * 512 +
                   cb * 128 + c8 * 8) = v;
      }
    }
  } else {
    const int blk2 = blk - 1600;            // 16 halo blocks
    const int b = blk2 >> 1, half = blk2 & 1;
    bf16x8 z;
#pragma unroll
    for (int j = 0; j < 8; ++j) z[j] = (bf16_t)0.f;
#pragma unroll
    for (int it = 0; it < 32; ++it) {
      int idx = it * 256 + t;
      int q = half * 128 + (idx >> 6);
      int c8 = idx & 63;
      int h, w;
      if (q < 78)       { h = 0;           w = q; }
      else if (q < 156) { h = 51;          w = q - 78; }
      else if (q < 206) { h = q - 156 + 1; w = 0; }
      else              { h = q - 206 + 1; w = 77; }
      *(bf16x8*)(Xp + ((size_t)(b * 52 + h) * 78 + w) * 512 + c8 * 8) = z;
    }
  }
}

// conv_w [512][512][3][3] f32 -> Wt [9][co][ci] bf16.
__global__ __launch_bounds__(256) void wtrans(const float* __restrict__ cw,
                                              bf16_t* __restrict__ Wt) {
  __shared__ bf16_t lw[4608];
  const int t = threadIdx.x;
  const int co = blockIdx.x;
  const float* src = cw + (size_t)co * 4608;
#pragma unroll
  for (int it = 0; it < 18; ++it) {
    int idx = it * 256 + t;
    lw[idx] = (bf16_t)src[idx];
  }
  __syncthreads();
#pragma unroll
  for (int s = 0; s < 9; ++s) {
    int ci = t * 2;
    bf16_t v0 = lw[ci * 9 + s], v1 = lw[(ci + 1) * 9 + s];
    bf16_t* dst = Wt + ((size_t)s * 512 + co) * 512 + ci;
    dst[0] = v0; dst[1] = v1;
  }
}

// cls_w [18][512], bbox_w [36][512] f32 -> Whb [64][512] bf16, rows permuted.
__global__ __launch_bounds__(256) void whb_build(const float* __restrict__ clsw,
                                                 const float* __restrict__ boxw,
                                                 bf16_t* __restrict__ Whb) {
  int t = blockIdx.x * 256 + threadIdx.x;   // 64*512 = 32768
  int ci = t & 511; int row = t >> 9;
  float v = 0.f;
  if (row < 18) {
    int a = row >> 1, logit = row & 1;
    v = clsw[(logit * 9 + a) * 512 + ci];
  } else if (row < 54) {
    v = boxw[(row - 18) * 512 + ci];
  }
  Whb[(size_t)row * 512 + ci] = (bf16_t)v;
}

// implicit-GEMM conv3x3: 256co x 256pos tile, BK=64, 8 waves (2Mx4N),
// double-buffered 128KiB LDS, 4-phase pipelined K-loop (72 K-tiles).
__global__ __launch_bounds__(512) void conv3x3(const bf16_t* __restrict__ Xp,
                                               const bf16_t* __restrict__ Wt,
                                               const float* __restrict__ convb,
                                               bf16_t* __restrict__ rc2) {
  __shared__ __align__(16) char smem[131072];  // buf0: A[0,32K) B[32K,64K); buf1 at 64K
  const int tid = threadIdx.x;
  const int lane = tid & 63;
  const int wv = tid >> 6;          // 0..7
  const int wm = wv >> 2;           // 0..1  (co half)
  const int wn = wv & 3;            // 0..3  (pos quarter)
  const int lm = lane & 15, lg = lane >> 4;

  // XCD swizzle: 240 blocks, 240%8==0 -> one image per XCD
  const int raw = blockIdx.x;
  const int wg = (raw & 7) * 30 + (raw >> 3);
  const int b = wg / 30;
  const int rem = wg - b * 30;
  const int co_base = (rem & 1) * 256;
  const int pos_base = (rem >> 1) * 256;

  // staging descriptors: chunk d = i*512+tid; row r=d>>3, phys p=d&7, logical c=p^(r&7)
  int aSrc[4], hB[4], wB[4], cB[4];
#pragma unroll
  for (int i = 0; i < 4; ++i) {
    int d = i * 512 + tid;
    int r = d >> 3, p = d & 7, c = p ^ (r & 7);
    aSrc[i] = (co_base + r) * 512 + c * 8;
    int m = pos_base + r; if (m > HW - 1) m = HW - 1;   // tail clamp (masked at store)
    hB[i] = m / 76; wB[i] = m - (m / 76) * 76; cB[i] = c * 8;
  }
  const bf16_t* XpB = Xp + (size_t)b * XP_IMG;

  // fragment read offsets (XOR-swizzled, conflict-free: lane&7 -> distinct chunk)
  int aOff[8], bOff[4], koffs[2];
#pragma unroll
  for (int m = 0; m < 8; ++m) aOff[m] = (wm * 128 + m * 16 + lm) * 128;
#pragma unroll
  for (int n = 0; n < 4; ++n) bOff[n] = 32768 + (wn * 64 + n * 16 + lm) * 128;
#pragma unroll
  for (int ks = 0; ks < 2; ++ks) koffs[ks] = ((ks * 4 + lg) ^ (lm & 7)) << 4;

  f32x4 acc[8][4];
#pragma unroll
  for (int i = 0; i < 8; ++i)
#pragma unroll
    for (int j = 0; j < 4; ++j) acc[i][j] = (f32x4){0.f, 0.f, 0.f, 0.f};

  // prologue: stage K-tile 0 (s=0, cb=0) into buf0
#pragma unroll
  for (int i = 0; i < 4; ++i)
    gload_lds16(Wt + aSrc[i], smem + (i * 512 + tid) * 16);
#pragma unroll
  for (int i = 0; i < 4; ++i)
    gload_lds16(XpB + (hB[i] * 78 + wB[i]) * 512 + cB[i],
                smem + 32768 + (i * 512 + tid) * 16);
  asm volatile("s_waitcnt vmcnt(0)" ::: "memory");
  __builtin_amdgcn_s_barrier();
  __builtin_amdgcn_sched_barrier(0);

  for (int kt = 0; kt < 72; ++kt) {            // K-tile = (s = kt>>3, cb = kt&7)
    const int cur = kt & 1;
    const char* Ab = smem + cur * 65536;       // bOff[] includes the +32768 B offset
    char* Anxt = smem + (cur ^ 1) * 65536;
    const int tn = kt + 1;
    const int sn = tn >> 3, cbn = tn & 7;

    bf16x8 pa[4], pb[4];

    // ---- phase 0: issue A-stage(t+1); read B(ks0)+A(mh0,ks0); MFMA acc[0..3]
    if (tn < 72) {
      const bf16_t* As = Wt + (size_t)sn * 262144 + cbn * 64;
#pragma unroll
      for (int i = 0; i < 4; ++i)
        gload_lds16(As + aSrc[i], Anxt + (i * 512 + tid) * 16);
    }
#pragma unroll
    for (int n = 0; n < 4; ++n) pb[n] = *(const bf16x8*)(Ab + bOff[n] + koffs[0]);
#pragma unroll
    for (int f = 0; f < 4; ++f) pa[f] = *(const bf16x8*)(Ab + aOff[f] + koffs[0]);
    __builtin_amdgcn_s_setprio(1);
#pragma unroll
    for (int f = 0; f < 4; ++f)
#pragma unroll
      for (int n = 0; n < 4; ++n)
        acc[f][n] = __builtin_amdgcn_mfma_f32_16x16x32_bf16(pa[f], pb[n], acc[f][n], 0, 0, 0);
    __builtin_amdgcn_s_setprio(0);
    __builtin_amdgcn_s_barrier();

    // ---- phase 1: issue B-stage(t+1); read A(mh1,ks0); MFMA acc[4..7] (pb held)
    if (tn < 72) {
      const int kh = sn / 3, kw = sn - kh * 3;
#pragma unroll
      for (int i = 0; i < 4; ++i) {
        int off = ((hB[i] + kh) * 78 + (wB[i] + kw)) * 512 + cB[i] + cbn * 64;
        gload_lds16(XpB + off, Anxt + 32768 + (i * 512 + tid) * 16);
      }
    }
#pragma unroll
    for (int f = 0; f < 4; ++f) pa[f] = *(const bf16x8*)(Ab + aOff[4 + f] + koffs[0]);
    __builtin_amdgcn_s_setprio(1);
#pragma unroll
    for (int f = 0; f < 4; ++f)
#pragma unroll
      for (int n = 0; n < 4; ++n)
        acc[4 + f][n] = __builtin_amdgcn_mfma_f32_16x16x32_bf16(pa[f], pb[n], acc[4 + f][n], 0, 0, 0);
    __builtin_amdgcn_s_setprio(0);
    __builtin_amdgcn_s_barrier();

    // ---- phase 2: read B(ks1)+A(mh0,ks1); MFMA acc[0..3]
#pragma unroll
    for (int n = 0; n < 4; ++n) pb[n] = *(const bf16x8*)(Ab + bOff[n] + koffs[1]);
#pragma unroll
    for (int f = 0; f < 4; ++f) pa[f] = *(const bf16x8*)(Ab + aOff[f] + koffs[1]);
    __builtin_amdgcn_s_setprio(1);
#pragma unroll
    for (int f = 0; f < 4; ++f)
#pragma unroll
      for (int n = 0; n < 4; ++n)
        acc[f][n] = __builtin_amdgcn_mfma_f32_16x16x32_bf16(pa[f], pb[n], acc[f][n], 0, 0, 0);
    __builtin_amdgcn_s_setprio(0);
    __builtin_amdgcn_s_barrier();

    // ---- phase 3: read A(mh1,ks1); MFMA acc[4..7]
#pragma unroll
    for (int f = 0; f < 4; ++f) pa[f] = *(const bf16x8*)(Ab + aOff[4 + f] + koffs[1]);
    __builtin_amdgcn_s_setprio(1);
#pragma unroll
    for (int f = 0; f < 4; ++f)
#pragma unroll
      for (int n = 0; n < 4; ++n)
        acc[4 + f][n] = __builtin_amdgcn_mfma_f32_16x16x32_bf16(pa[f], pb[n], acc[4 + f][n], 0, 0, 0);
    __builtin_amdgcn_s_setprio(0);

    // ---- boundary: per-wave drain of t+1's stage loads, then全-wave visibility
    asm volatile("s_waitcnt vmcnt(0)" ::: "memory");
    __builtin_amdgcn_s_barrier();
    __builtin_amdgcn_sched_barrier(0);
  }

  // epilogue: bias + ReLU, store NHWC rc2[(b*HW+pos)][co], 8B per fragment
  const size_t outRow = (size_t)b * HW;
#pragma unroll
  for (int m = 0; m < 8; ++m) {
    const int co = co_base + wm * 128 + m * 16 + lg * 4;
    const float4 bias = *(const float4*)(convb + co);
#pragma unroll
    for (int n = 0; n < 4; ++n) {
      const int pos = pos_base + wn * 64 + n * 16 + lm;
      if (pos < HW) {
        bf16x4 v;
        float z0 = acc[m][n][0] + bias.x; v[0] = (bf16_t)(z0 > 0.f ? z0 : 0.f);
        float z1 = acc[m][n][1] + bias.y; v[1] = (bf16_t)(z1 > 0.f ? z1 : 0.f);
        float z2 = acc[m][n][2] + bias.z; v[2] = (bf16_t)(z2 > 0.f ? z2 : 0.f);
        float z3 = acc[m][n][3] + bias.w; v[3] = (bf16_t)(z3 > 0.f ? z3 : 0.f);
        *(bf16x4*)(rc2 + (outRow + pos) * 512 + co) = v;
      }
    }
  }
}

// heads: C[64co][128pos] = Whb[64][512] x rc2[pos][512], fused bias/softmax/store.
__global__ __launch_bounds__(256) void heads_mfma(const bf16_t* __restrict__ rc2,
                                                  const bf16_t* __restrict__ Whb,
                                                  const float* __restrict__ clsb,
                                                  const float* __restrict__ boxb,
                                                  float* __restrict__ out) {
  __shared__ __align__(16) char smem[24576];  // A:[0,8K) B:[8K,24K)
  const int t = threadIdx.x, lane = t & 63, wv = t >> 6;
  const int lm = lane & 15, lg = lane >> 4, lx = lane & 7;
  const int pos_base = blockIdx.x * 128;

  int aSrc[2], bSrc[4];
#pragma unroll
  for (int i = 0; i < 2; ++i) {
    int d = i * 256 + t;
    int r = d >> 3, p = d & 7, c = p ^ (r & 7);
    aSrc[i] = r * 512 + c * 8;
  }
#pragma unroll
  for (int i = 0; i < 4; ++i) {
    int d = i * 256 + t;
    int r = d >> 3, p = d & 7, c = p ^ (r & 7);
    int pg = pos_base + r; if (pg > NPOS - 1) pg = NPOS - 1;
    bSrc[i] = pg * 512 + c * 8;
  }

  f32x4 acc[4][2];
#pragma unroll
  for (int i = 0; i < 4; ++i)
#pragma unroll
    for (int j = 0; j < 2; ++j) acc[i][j] = (f32x4){0.f, 0.f, 0.f, 0.f};

  for (int cb = 0; cb < 8; ++cb) {
    __syncthreads();
#pragma unroll
    for (int i = 0; i < 2; ++i) {
      int d = i * 256 + t;
      gload_lds16(Whb + aSrc[i] + cb * 64, &smem[d * 16]);
    }
#pragma unroll
    for (int i = 0; i < 4; ++i) {
      int d = i * 256 + t;
      gload_lds16(rc2 + (size_t)bSrc[i] + cb * 64, &smem[8192 + d * 16]);
    }
    __syncthreads();
#pragma unroll
    for (int ks = 0; ks < 2; ++ks) {
      const int koff = ((ks * 4 + lg) ^ lx) << 4;
      bf16x8 af[4], bfr[2];
#pragma unroll
      for (int f = 0; f < 4; ++f)
        af[f] = *(const bf16x8*)&smem[(f * 16 + lm) * 128 + koff];
#pragma unroll
      for (int f = 0; f < 2; ++f)
        bfr[f] = *(const bf16x8*)&smem[8192 + (wv * 32 + f * 16 + lm) * 128 + koff];
#pragma unroll
      for (int fa = 0; fa < 4; ++fa)
#pragma unroll
        for (int fb = 0; fb < 2; ++fb)
          acc[fa][fb] = __builtin_amdgcn_mfma_f32_16x16x32_bf16(
              af[fa], bfr[fb], acc[fa][fb], 0, 0, 0);
    }
  }

  float* boxOut = out + (size_t)8 * 18 * HW;
#pragma unroll
  for (int fb = 0; fb < 2; ++fb) {
    const int pg = pos_base + wv * 32 + fb * 16 + lm;
    if (pg < NPOS) {
      const int b = pg / HW;
      const int m = pg - b * HW;
#pragma unroll
      for (int fa = 0; fa < 4; ++fa) {
        const int base = fa * 16 + lg * 4;
#pragma unroll
        for (int pr = 0; pr < 2; ++pr) {
          const int row0 = base + pr * 2;
          const float v0 = acc[fa][fb][pr * 2];
          const float v1 = acc[fa][fb][pr * 2 + 1];
          if (row0 < 18) {
            const int a = row0 >> 1;
            const float s0 = v0 + clsb[a];
            const float s1 = v1 + clsb[9 + a];
            const float mx = fmaxf(s0, s1);
            const float e0 = expf(s0 - mx), e1 = expf(s1 - mx);
            const float inv = 1.0f / (e0 + e1);
            out[((size_t)(b * 18 + a)) * HW + m] = e0 * inv;
            out[((size_t)(b * 18 + 9 + a)) * HW + m] = e1 * inv;
          } else if (row0 < 54) {
            const int c0 = row0 - 18;
            boxOut[((size_t)(b * 36 + c0)) * HW + m] = v0 + boxb[c0];
            boxOut[((size_t)(b * 36 + c0 + 1)) * HW + m] = v1 + boxb[c0 + 1];
          }
        }
      }
    }
  }
}

extern "C" void kernel_launch(void* const* d_in, const int* in_sizes, int n_in,
                              void* d_out, int out_size, void* d_ws, size_t ws_size,
                              hipStream_t stream) {
  (void)in_sizes; (void)n_in; (void)out_size; (void)ws_size;
  const float* base_feat = (const float*)d_in[0];
  const float* conv_w = (const float*)d_in[4];
  const float* conv_b = (const float*)d_in[5];
  const float* cls_w  = (const float*)d_in[6];
  const float* cls_b  = (const float*)d_in[7];
  const float* bbox_w = (const float*)d_in[8];
  const float* bbox_b = (const float*)d_in[9];

  char* ws = (char*)d_ws;
  bf16_t* Xp  = (bf16_t*)(ws);                 // 8*52*78*512*2   = 33,226,752 B
  bf16_t* Wt  = (bf16_t*)(ws + 33226752);      // 9*512*512*2     =  4,718,592 B
  bf16_t* rc2 = (bf16_t*)(ws + 37945344);      // 30400*512*2     = 31,129,600 B (NHWC)
  bf16_t* Whb = (bf16_t*)(ws + 69074944);      // 64*512*2        =     65,536 B

  hipLaunchKernelGGL(pad_nhwc,   dim3(1616), dim3(256), 0, stream, base_feat, Xp);
  hipLaunchKernelGGL(wtrans,     dim3(512),  dim3(256), 0, stream, conv_w, Wt);
  hipLaunchKernelGGL(whb_build,  dim3(128),  dim3(256), 0, stream, cls_w, bbox_w, Whb);
  hipLaunchKernelGGL(conv3x3,    dim3(240),  dim3(512), 0, stream, Xp, Wt, conv_b, rc2);
  hipLaunchKernelGGL(heads_mfma, dim3(238),  dim3(256), 0, stream, rc2, Whb, cls_b, bbox_b,
                     (float*)d_out);
}